// Round 1
// baseline (6276.841 us; speedup 1.0000x reference)
//
#include <hip/hip_runtime.h>
#include <hip/hip_bf16.h>

// Problem dims
constexpr int NB = 128;   // batch
constexpr int NT = 512;   // seq len
constexpr int NE = 256;   // embed dim
constexpr int NH = 512;   // hidden
constexpr int NV = 64;    // vocab
constexpr int NP = 128;   // output proj dim

typedef unsigned short u16;
typedef __attribute__((ext_vector_type(8))) short bf16x8v;   // 8 bf16 (4 VGPRs) MFMA operand
typedef __attribute__((ext_vector_type(4))) float f32x4v;    // MFMA accumulator

__device__ __forceinline__ u16 f2bf(float x) {
  unsigned u = __builtin_bit_cast(unsigned, x);
  unsigned r = (u + 0x7fffu + ((u >> 16) & 1u)) >> 16;  // RNE
  return (u16)r;
}
__device__ __forceinline__ float bf2f(u16 b) {
  return __builtin_bit_cast(float, (unsigned)b << 16);
}

// ---------------------------------------------------------------------------
// proj[v][j] = emb_table[v] . W_xh0[:,j] + b_xh0[j]    (f32, exact input drive)
// grid: NV*2 blocks x 256 threads
__global__ __launch_bounds__(256) void proj_kernel(
    const float* __restrict__ emb, const float* __restrict__ W_xh0,
    const float* __restrict__ b_xh0, float* __restrict__ proj) {
  int v = blockIdx.x >> 1;
  int j = ((blockIdx.x & 1) << 8) + threadIdx.x;
  float acc = b_xh0[j];
  const float* er = emb + v * NE;
  for (int e = 0; e < NE; ++e) acc += er[e] * W_xh0[e * NH + j];
  proj[v * NH + j] = acc;
}

// dst[c][r] = bf16(src[r][c])  (transpose + convert); C is a power of two
__global__ __launch_bounds__(256) void transpose_bf16_kernel(
    const float* __restrict__ src, u16* __restrict__ dst, int R, int logC) {
  int idx = blockIdx.x * 256 + threadIdx.x;
  int C = 1 << logC;
  if (idx >= R * C) return;
  int r = idx >> logC;
  int c = idx & (C - 1);
  dst[c * R + r] = f2bf(src[idx]);
}

// ---------------------------------------------------------------------------
// One pipeline stage s (0..NT):
//   blocks [0,32):  layer0 -> h0(s)      (active for s < NT)
//   blocks [32,64): layer1 -> h1(s-1)    (active for s >= 1)
// h0 double-buffered by parity of s; h1 history lives in h1_all.
constexpr int NBLK_L = 32;
constexpr int NC = 16;        // output columns per block
constexpr int KPAD = 520;     // padded LDS row (bank-uniform ds_read_b128)

__global__ __launch_bounds__(256) void stage_kernel(
    int s,
    const int* __restrict__ src, const int* __restrict__ lens,
    const float* __restrict__ proj,
    const u16* __restrict__ Wt_hh0,   // [NH][NH] = W_hh0^T, bf16
    const u16* __restrict__ Wt_xh1,
    const u16* __restrict__ Wt_hh1,
    const float* __restrict__ b_xh1,
    u16* __restrict__ h0_bufs,        // [2][NB][NH]
    u16* __restrict__ h1_all)         // [NT][NB][NH]
{
  __shared__ union {
    struct { u16 w[NC][KPAD]; float pj[NV][NC]; int srcv[NB]; int len[NB]; } l0;
    struct { u16 wx[NC][KPAD]; u16 wh[NC][KPAD]; float b1[NC]; int len[NB]; } l1;
  } sm;

  const int tid = threadIdx.x;
  const int lane = tid & 63, wave = tid >> 6;
  const int lq = lane >> 4, lr = lane & 15;
  const int m0 = wave * 32;

  u16* h0_cur = h0_bufs + (s & 1) * (NB * NH);
  const u16* h0_prev = h0_bufs + ((s + 1) & 1) * (NB * NH);

  if (blockIdx.x < NBLK_L) {
    // -------------------- layer 0 --------------------
    if (s >= NT) return;
    const int c0 = blockIdx.x * NC;
#pragma unroll
    for (int it = 0; it < 4; ++it) {          // 16 rows x 512 k of bf16 = 1024 x 16B
      int ch = it * 256 + tid;
      int n = ch >> 6, k8 = (ch & 63) * 8;
      *(uint4*)&sm.l0.w[n][k8] = *(const uint4*)&Wt_hh0[(c0 + n) * NH + k8];
    }
#pragma unroll
    for (int it = 0; it < 4; ++it) {          // 64 x 16 f32
      int idx = it * 256 + tid;
      sm.l0.pj[idx >> 4][idx & 15] = proj[(idx >> 4) * NH + c0 + (idx & 15)];
    }
    if (tid < NB) { sm.l0.srcv[tid] = src[tid * NT + s]; sm.l0.len[tid] = lens[tid]; }
    __syncthreads();

    f32x4v acc0 = {0.f, 0.f, 0.f, 0.f}, acc1 = {0.f, 0.f, 0.f, 0.f};
    if (s > 0) {
      const u16* a0p = h0_prev + (m0 + lr) * NH;
      const u16* a1p = a0p + 16 * NH;
      const u16* bp = &sm.l0.w[lr][0];
#pragma unroll 4
      for (int kt = 0; kt < 16; ++kt) {
        int kb = kt * 32 + lq * 8;
        bf16x8v a0 = *(const bf16x8v*)(a0p + kb);
        bf16x8v a1 = *(const bf16x8v*)(a1p + kb);
        bf16x8v bb = *(const bf16x8v*)(bp + kb);
        acc0 = __builtin_amdgcn_mfma_f32_16x16x32_bf16(a0, bb, acc0, 0, 0, 0);
        acc1 = __builtin_amdgcn_mfma_f32_16x16x32_bf16(a1, bb, acc1, 0, 0, 0);
      }
    }
#pragma unroll
    for (int mi = 0; mi < 2; ++mi) {
      f32x4v acc = mi ? acc1 : acc0;
#pragma unroll
      for (int i = 0; i < 4; ++i) {
        int r = m0 + mi * 16 + lq * 4 + i;            // batch row
        int j = c0 + lr;                               // hidden col
        float pre = acc[i] + sm.l0.pj[sm.l0.srcv[r]][lr];
        u16 outv = (s < sm.l0.len[r]) ? f2bf(tanhf(pre)) : h0_prev[r * NH + j];
        h0_cur[r * NH + j] = outv;
      }
    }
  } else {
    // -------------------- layer 1 (t = s-1) --------------------
    const int t = s - 1;
    if (t < 0) return;
    const int c0 = (blockIdx.x - NBLK_L) * NC;
#pragma unroll
    for (int it = 0; it < 8; ++it) {          // two 16x512 bf16 slices = 2048 x 16B
      int ch = it * 256 + tid;
      int mat = ch >> 10, rest = ch & 1023;
      int n = rest >> 6, k8 = (rest & 63) * 8;
      const u16* sw = (mat ? Wt_hh1 : Wt_xh1) + (c0 + n) * NH + k8;
      u16* dw = (mat ? &sm.l1.wh[n][0] : &sm.l1.wx[n][0]) + k8;
      *(uint4*)dw = *(const uint4*)sw;
    }
    if (tid < NC) sm.l1.b1[tid] = b_xh1[c0 + tid];
    if (tid < NB) sm.l1.len[tid] = lens[tid];
    __syncthreads();

    const u16* h0t = h0_prev;                           // h0(t) lives in buf[(s-1)&1]
    const u16* h1p = h1_all + (t - 1) * (NB * NH);      // valid iff t > 0
    f32x4v acc0 = {0.f, 0.f, 0.f, 0.f}, acc1 = {0.f, 0.f, 0.f, 0.f};
    {
      const u16* a0p = h0t + (m0 + lr) * NH;
      const u16* a1p = a0p + 16 * NH;
      const u16* bp = &sm.l1.wx[lr][0];
#pragma unroll 4
      for (int kt = 0; kt < 16; ++kt) {
        int kb = kt * 32 + lq * 8;
        bf16x8v a0 = *(const bf16x8v*)(a0p + kb);
        bf16x8v a1 = *(const bf16x8v*)(a1p + kb);
        bf16x8v bb = *(const bf16x8v*)(bp + kb);
        acc0 = __builtin_amdgcn_mfma_f32_16x16x32_bf16(a0, bb, acc0, 0, 0, 0);
        acc1 = __builtin_amdgcn_mfma_f32_16x16x32_bf16(a1, bb, acc1, 0, 0, 0);
      }
    }
    if (t > 0) {
      const u16* a0p = h1p + (m0 + lr) * NH;
      const u16* a1p = a0p + 16 * NH;
      const u16* bp = &sm.l1.wh[lr][0];
#pragma unroll 4
      for (int kt = 0; kt < 16; ++kt) {
        int kb = kt * 32 + lq * 8;
        bf16x8v a0 = *(const bf16x8v*)(a0p + kb);
        bf16x8v a1 = *(const bf16x8v*)(a1p + kb);
        bf16x8v bb = *(const bf16x8v*)(bp + kb);
        acc0 = __builtin_amdgcn_mfma_f32_16x16x32_bf16(a0, bb, acc0, 0, 0, 0);
        acc1 = __builtin_amdgcn_mfma_f32_16x16x32_bf16(a1, bb, acc1, 0, 0, 0);
      }
    }
    u16* h1out = h1_all + t * (NB * NH);
#pragma unroll
    for (int mi = 0; mi < 2; ++mi) {
      f32x4v acc = mi ? acc1 : acc0;
#pragma unroll
      for (int i = 0; i < 4; ++i) {
        int r = m0 + mi * 16 + lq * 4 + i;
        int j = c0 + lr;
        float pre = acc[i] + sm.l1.b1[lr];
        u16 outv = (t < sm.l1.len[r]) ? f2bf(tanhf(pre)) : h1p[r * NH + j];
        h1out[r * NH + j] = outv;
      }
    }
  }
}

// ---------------------------------------------------------------------------
// logits[b][t][p] = h1_all[t][b][:] . fc_w[:,p] + fc_b[p]
// one block per t: 128 b-rows x 128 p-cols, K = 512
__global__ __launch_bounds__(256) void out_gemm(
    const u16* __restrict__ h1_all, const u16* __restrict__ fc_wT,
    const float* __restrict__ fc_b, float* __restrict__ out)
{
  const int t = blockIdx.x;
  const int tid = threadIdx.x, lane = tid & 63, wave = tid >> 6;
  const int lq = lane >> 4, lr = lane & 15;
  const int m0 = wave * 32;
  f32x4v acc[2][8];
#pragma unroll
  for (int a = 0; a < 2; ++a)
#pragma unroll
    for (int b = 0; b < 8; ++b) acc[a][b] = (f32x4v){0.f, 0.f, 0.f, 0.f};

  const u16* a0p = h1_all + (t * NB + m0 + lr) * NH;
  const u16* a1p = a0p + 16 * NH;
#pragma unroll 2
  for (int kt = 0; kt < 16; ++kt) {
    int kb = kt * 32 + lq * 8;
    bf16x8v a0 = *(const bf16x8v*)(a0p + kb);
    bf16x8v a1 = *(const bf16x8v*)(a1p + kb);
#pragma unroll
    for (int ni = 0; ni < 8; ++ni) {
      bf16x8v bb = *(const bf16x8v*)(fc_wT + (ni * 16 + lr) * NH + kb);
      acc[0][ni] = __builtin_amdgcn_mfma_f32_16x16x32_bf16(a0, bb, acc[0][ni], 0, 0, 0);
      acc[1][ni] = __builtin_amdgcn_mfma_f32_16x16x32_bf16(a1, bb, acc[1][ni], 0, 0, 0);
    }
  }
#pragma unroll
  for (int mi = 0; mi < 2; ++mi)
#pragma unroll
    for (int ni = 0; ni < 8; ++ni)
#pragma unroll
      for (int i = 0; i < 4; ++i) {
        int b_ = m0 + mi * 16 + lq * 4 + i;
        int p = ni * 16 + lr;
        out[(b_ * NT + t) * NP + p] = acc[mi][ni][i] + fc_b[p];
      }
}

// ---------------------------------------------------------------------------
extern "C" void kernel_launch(void* const* d_in, const int* in_sizes, int n_in,
                              void* d_out, int out_size, void* d_ws, size_t ws_size,
                              hipStream_t stream) {
  const int*   src   = (const int*)  d_in[0];
  const int*   lens  = (const int*)  d_in[1];
  const float* emb   = (const float*)d_in[2];
  const float* W_xh0 = (const float*)d_in[3];
  const float* b_xh0 = (const float*)d_in[4];
  const float* W_hh0 = (const float*)d_in[5];
  const float* W_xh1 = (const float*)d_in[6];
  const float* b_xh1 = (const float*)d_in[7];
  const float* W_hh1 = (const float*)d_in[8];
  const float* fc_w  = (const float*)d_in[9];
  const float* fc_b  = (const float*)d_in[10];
  float* out = (float*)d_out;

  char* ws = (char*)d_ws;
  auto alloc = [&](size_t bytes) { char* p = ws; ws += (bytes + 255) & ~size_t(255); return p; };
  float* proj   = (float*)alloc(NV * NH * 4);
  u16* Wt_hh0   = (u16*)  alloc(NH * NH * 2);
  u16* Wt_xh1   = (u16*)  alloc(NH * NH * 2);
  u16* Wt_hh1   = (u16*)  alloc(NH * NH * 2);
  u16* fc_wT    = (u16*)  alloc(NP * NH * 2);
  u16* h0_bufs  = (u16*)  alloc(2 * NB * NH * 2);
  u16* h1_all   = (u16*)  alloc((size_t)NT * NB * NH * 2);

  proj_kernel<<<NV * 2, 256, 0, stream>>>(emb, W_xh0, b_xh0, proj);
  transpose_bf16_kernel<<<(NH * NH + 255) / 256, 256, 0, stream>>>(W_hh0, Wt_hh0, NH, 9);
  transpose_bf16_kernel<<<(NH * NH + 255) / 256, 256, 0, stream>>>(W_xh1, Wt_xh1, NH, 9);
  transpose_bf16_kernel<<<(NH * NH + 255) / 256, 256, 0, stream>>>(W_hh1, Wt_hh1, NH, 9);
  transpose_bf16_kernel<<<(NH * NP + 255) / 256, 256, 0, stream>>>(fc_w, fc_wT, NH, 7);

  for (int s = 0; s <= NT; ++s)
    stage_kernel<<<2 * NBLK_L, 256, 0, stream>>>(s, src, lens, proj, Wt_hh0, Wt_xh1,
                                                 Wt_hh1, b_xh1, h0_bufs, h1_all);

  out_gemm<<<NT, 256, 0, stream>>>(h1_all, fc_wT, fc_b, out);
}

// Round 2
// 6207.312 us; speedup vs baseline: 1.0112x; 1.0112x over previous
//
#include <hip/hip_runtime.h>
#include <hip/hip_bf16.h>

// Problem dims
constexpr int NB = 128;   // batch
constexpr int NT = 512;   // seq len
constexpr int NE = 256;   // embed dim
constexpr int NH = 512;   // hidden
constexpr int NV = 64;    // vocab
constexpr int NP = 128;   // output proj dim

// Persistent-kernel decomposition: 8 independent row groups of 16 batch rows.
// Per group: 8 layer-0 blocks + 8 layer-1 blocks, each owning a 64-col slice
// whose weights stay LDS-resident for the entire sequence.
constexpr int GROUPS = 8;
constexpr int MR     = 16;    // batch rows per group
constexpr int NCS    = 64;    // hidden cols per block slice
constexpr int SLICES = 8;     // NH / NCS
constexpr int NBLK   = GROUPS * 2 * SLICES;   // 128 blocks

typedef unsigned short u16;
typedef __attribute__((ext_vector_type(8))) short bf16x8v;   // 8 bf16 (4 VGPRs)
typedef __attribute__((ext_vector_type(4))) float f32x4v;    // MFMA accumulator

__device__ __forceinline__ u16 f2bf(float x) {
  unsigned u = __builtin_bit_cast(unsigned, x);
  return (u16)((u + 0x7fffu + ((u >> 16) & 1u)) >> 16);  // RNE
}

// ---------------------------------------------------------------------------
// proj[v][j] = emb_table[v] . W_xh0[:,j] + b_xh0[j]    (f32, exact input drive)
__global__ __launch_bounds__(256) void proj_kernel(
    const float* __restrict__ emb, const float* __restrict__ W_xh0,
    const float* __restrict__ b_xh0, float* __restrict__ proj) {
  int v = blockIdx.x >> 1;
  int j = ((blockIdx.x & 1) << 8) + threadIdx.x;
  float acc = b_xh0[j];
  const float* er = emb + v * NE;
  for (int e = 0; e < NE; ++e) acc += er[e] * W_xh0[e * NH + j];
  proj[v * NH + j] = acc;
}

// dst[c][r] = bf16(src[r][c])  (transpose + convert); C is a power of two
__global__ __launch_bounds__(256) void transpose_bf16_kernel(
    const float* __restrict__ src, u16* __restrict__ dst, int R, int logC) {
  int idx = blockIdx.x * 256 + threadIdx.x;
  int C = 1 << logC;
  if (idx >= R * C) return;
  int r = idx >> logC;
  int c = idx & (C - 1);
  dst[c * R + r] = f2bf(src[idx]);
}

__global__ void init_bar_kernel(int* bar) {
  bar[threadIdx.x] = 0;   // 256 ints cover 8 groups x 32-int stride
}

// ---------------------------------------------------------------------------
// Persistent skewed-pipeline RNN: stage s computes h0(s) [layer-0 blocks] and
// h1(s-1) [layer-1 blocks]; one 16-block group barrier per stage.
__global__ __launch_bounds__(256) void rnn_persist(
    const int* __restrict__ src, const int* __restrict__ lens,
    const float* __restrict__ proj,
    const u16* __restrict__ Wt_hh0,   // [NH][NH] = W^T, bf16
    const u16* __restrict__ Wt_xh1,
    const u16* __restrict__ Wt_hh1,
    const float* __restrict__ b_xh1,
    u16* __restrict__ h0_bufs,        // [2][NB][NH]
    u16* __restrict__ h1_all,         // [NT][NB][NH]
    int* bar)                         // 8 groups x 32-int stride: {cnt, flag}
{
  __shared__ union {
    struct { u16 w[NCS * NH]; float pj[NV * NCS]; } l0;   // 64KB + 16KB
    struct { u16 wx[NCS * NH]; u16 wh[NCS * NH]; } l1;    // 128KB
  } sm;

  const int bid = blockIdx.x;
  const int g = bid & (GROUPS - 1);
  const int u = bid >> 3;                 // 0..15 within group
  const bool is_l1 = (u >= SLICES);
  const int slice = is_l1 ? (u - SLICES) : u;
  const int c0 = slice * NCS;
  const int r0 = g * MR;

  const int tid = threadIdx.x;
  const int lane = tid & 63, wave = tid >> 6;
  const int lq = lane >> 4, lr = lane & 15;
  const int n0 = wave * 16;               // col sub-tile within slice

  int* cnt = bar + g * 32;
  int* flg = cnt + 1;

  // ---- one-time LDS staging (XOR-swizzled: row stride 1024B would be a
  //      same-bank ds_read_b128 pattern; k8 ^ ((row&7)<<3) spreads rows) ----
  if (!is_l1) {
#pragma unroll
    for (int it = 0; it < 16; ++it) {     // 64 cols x 512 k bf16 = 4096 chunks
      int ch = it * 256 + tid;
      int n = ch >> 6, k8 = (ch & 63) * 8;
      *(uint4*)&sm.l0.w[n * NH + (k8 ^ ((n & 7) << 3))] =
          *(const uint4*)&Wt_hh0[(c0 + n) * NH + k8];
    }
#pragma unroll
    for (int it = 0; it < 4; ++it) {      // proj slice 64 x 64 f32
      int ch = it * 256 + tid;
      int v = ch >> 4, j4 = (ch & 15) * 4;
      *(float4*)&sm.l0.pj[v * NCS + j4] = *(const float4*)&proj[v * NH + c0 + j4];
    }
  } else {
#pragma unroll
    for (int it = 0; it < 32; ++it) {     // 2 mats x 4096 chunks
      int ch = it * 256 + tid;
      int mat = ch >> 12, rest = ch & 4095;
      int n = rest >> 6, k8 = (rest & 63) * 8;
      const u16* sw = (mat ? Wt_hh1 : Wt_xh1) + (c0 + n) * NH + k8;
      u16* dw = (mat ? sm.l1.wh : sm.l1.wx) + n * NH + (k8 ^ ((n & 7) << 3));
      *(uint4*)dw = *(const uint4*)sw;
    }
  }
  __syncthreads();

  int rr[4], ln[4];
#pragma unroll
  for (int i = 0; i < 4; ++i) { rr[i] = r0 + lq * 4 + i; ln[i] = lens[rr[i]]; }
  const int jj = c0 + n0 + lr;            // global hidden col this lane owns
  const float bcol = is_l1 ? b_xh1[jj] : 0.f;
  const int bswz = (lr & 7) << 3;
  const size_t HS = (size_t)NB * NH;

  for (int s = 0; s <= NT; ++s) {
    const u16* h0_prev = h0_bufs + ((s + 1) & 1) * HS;   // h0(s-1)
    if (!is_l1) {
      if (s < NT) {
        u16* h0_cur = h0_bufs + (s & 1) * HS;
        f32x4v acc = {0.f, 0.f, 0.f, 0.f};
        if (s > 0) {
          const u16* ap = h0_prev + (r0 + lr) * NH;
#pragma unroll 4
          for (int kt = 0; kt < 16; ++kt) {
            int kb = kt * 32 + lq * 8;
            bf16x8v a = *(const bf16x8v*)(ap + kb);
            bf16x8v b = *(const bf16x8v*)&sm.l0.w[(n0 + lr) * NH + (kb ^ bswz)];
            acc = __builtin_amdgcn_mfma_f32_16x16x32_bf16(a, b, acc, 0, 0, 0);
          }
        }
#pragma unroll
        for (int i = 0; i < 4; ++i) {
          int r = rr[i];
          int v = src[r * NT + s];
          float pre = acc[i] + sm.l0.pj[v * NCS + n0 + lr];
          u16 o = (s < ln[i]) ? f2bf(tanhf(pre)) : h0_prev[r * NH + jj];
          h0_cur[r * NH + jj] = o;
        }
      }
    } else if (s >= 1) {
      const int t = s - 1;
      f32x4v acc = {0.f, 0.f, 0.f, 0.f};
      {
        const u16* ap = h0_prev + (r0 + lr) * NH;        // h0(t)
#pragma unroll 4
        for (int kt = 0; kt < 16; ++kt) {
          int kb = kt * 32 + lq * 8;
          bf16x8v a = *(const bf16x8v*)(ap + kb);
          bf16x8v b = *(const bf16x8v*)&sm.l1.wx[(n0 + lr) * NH + (kb ^ bswz)];
          acc = __builtin_amdgcn_mfma_f32_16x16x32_bf16(a, b, acc, 0, 0, 0);
        }
      }
      const u16* h1pv = h1_all + (size_t)(t > 0 ? t - 1 : 0) * HS;
      if (t > 0) {
        const u16* ap = h1pv + (r0 + lr) * NH;
#pragma unroll 4
        for (int kt = 0; kt < 16; ++kt) {
          int kb = kt * 32 + lq * 8;
          bf16x8v a = *(const bf16x8v*)(ap + kb);
          bf16x8v b = *(const bf16x8v*)&sm.l1.wh[(n0 + lr) * NH + (kb ^ bswz)];
          acc = __builtin_amdgcn_mfma_f32_16x16x32_bf16(a, b, acc, 0, 0, 0);
        }
      }
      u16* h1out = h1_all + (size_t)t * HS;
#pragma unroll
      for (int i = 0; i < 4; ++i) {
        int r = rr[i];
        float pre = acc[i] + bcol;
        u16 o = (t < ln[i]) ? f2bf(tanhf(pre)) : h1pv[r * NH + jj];
        h1out[r * NH + jj] = o;
      }
    }

    // ---- per-group barrier (16 blocks), agent scope for cross-XCD safety ----
    if (s < NT) {
      __syncthreads();
      if (tid == 0) {
        int prev = __hip_atomic_fetch_add(cnt, 1, __ATOMIC_ACQ_REL,
                                          __HIP_MEMORY_SCOPE_AGENT);
        if (prev == 2 * SLICES - 1) {
          __hip_atomic_store(cnt, 0, __ATOMIC_RELAXED, __HIP_MEMORY_SCOPE_AGENT);
          __hip_atomic_store(flg, s + 1, __ATOMIC_RELEASE, __HIP_MEMORY_SCOPE_AGENT);
        } else {
          while (__hip_atomic_load(flg, __ATOMIC_ACQUIRE,
                                   __HIP_MEMORY_SCOPE_AGENT) < s + 1) {}
        }
      }
      __syncthreads();
    }
  }
}

// ---------------------------------------------------------------------------
// logits[b][t][p] = h1_all[t][b][:] . fc_w[:,p] + fc_b[p]
__global__ __launch_bounds__(256) void out_gemm(
    const u16* __restrict__ h1_all, const u16* __restrict__ fc_wT,
    const float* __restrict__ fc_b, float* __restrict__ out)
{
  const int t = blockIdx.x;
  const int tid = threadIdx.x, lane = tid & 63, wave = tid >> 6;
  const int lq = lane >> 4, lr = lane & 15;
  const int m0 = wave * 32;
  f32x4v acc[2][8];
#pragma unroll
  for (int a = 0; a < 2; ++a)
#pragma unroll
    for (int b = 0; b < 8; ++b) acc[a][b] = (f32x4v){0.f, 0.f, 0.f, 0.f};

  const u16* a0p = h1_all + ((size_t)t * NB + m0 + lr) * NH;
  const u16* a1p = a0p + 16 * NH;
#pragma unroll 2
  for (int kt = 0; kt < 16; ++kt) {
    int kb = kt * 32 + lq * 8;
    bf16x8v a0 = *(const bf16x8v*)(a0p + kb);
    bf16x8v a1 = *(const bf16x8v*)(a1p + kb);
#pragma unroll
    for (int ni = 0; ni < 8; ++ni) {
      bf16x8v bb = *(const bf16x8v*)(fc_wT + (ni * 16 + lr) * NH + kb);
      acc[0][ni] = __builtin_amdgcn_mfma_f32_16x16x32_bf16(a0, bb, acc[0][ni], 0, 0, 0);
      acc[1][ni] = __builtin_amdgcn_mfma_f32_16x16x32_bf16(a1, bb, acc[1][ni], 0, 0, 0);
    }
  }
#pragma unroll
  for (int mi = 0; mi < 2; ++mi)
#pragma unroll
    for (int ni = 0; ni < 8; ++ni)
#pragma unroll
      for (int i = 0; i < 4; ++i) {
        int b_ = m0 + mi * 16 + lq * 4 + i;
        int p = ni * 16 + lr;
        out[((size_t)b_ * NT + t) * NP + p] = acc[mi][ni][i] + fc_b[p];
      }
}

// ---------------------------------------------------------------------------
extern "C" void kernel_launch(void* const* d_in, const int* in_sizes, int n_in,
                              void* d_out, int out_size, void* d_ws, size_t ws_size,
                              hipStream_t stream) {
  const int*   src   = (const int*)  d_in[0];
  const int*   lens  = (const int*)  d_in[1];
  const float* emb   = (const float*)d_in[2];
  const float* W_xh0 = (const float*)d_in[3];
  const float* b_xh0 = (const float*)d_in[4];
  const float* W_hh0 = (const float*)d_in[5];
  const float* W_xh1 = (const float*)d_in[6];
  const float* b_xh1 = (const float*)d_in[7];
  const float* W_hh1 = (const float*)d_in[8];
  const float* fc_w  = (const float*)d_in[9];
  const float* fc_b  = (const float*)d_in[10];
  float* out = (float*)d_out;

  char* ws = (char*)d_ws;
  auto alloc = [&](size_t bytes) { char* p = ws; ws += (bytes + 255) & ~size_t(255); return p; };
  float* proj   = (float*)alloc(NV * NH * 4);
  u16* Wt_hh0   = (u16*)  alloc(NH * NH * 2);
  u16* Wt_xh1   = (u16*)  alloc(NH * NH * 2);
  u16* Wt_hh1   = (u16*)  alloc(NH * NH * 2);
  u16* fc_wT    = (u16*)  alloc(NP * NH * 2);
  u16* h0_bufs  = (u16*)  alloc(2 * NB * NH * 2);
  u16* h1_all   = (u16*)  alloc((size_t)NT * NB * NH * 2);
  int* bar      = (int*)  alloc(1024);

  proj_kernel<<<NV * 2, 256, 0, stream>>>(emb, W_xh0, b_xh0, proj);
  transpose_bf16_kernel<<<(NH * NH + 255) / 256, 256, 0, stream>>>(W_hh0, Wt_hh0, NH, 9);
  transpose_bf16_kernel<<<(NH * NH + 255) / 256, 256, 0, stream>>>(W_xh1, Wt_xh1, NH, 9);
  transpose_bf16_kernel<<<(NH * NH + 255) / 256, 256, 0, stream>>>(W_hh1, Wt_hh1, NH, 9);
  transpose_bf16_kernel<<<(NH * NP + 255) / 256, 256, 0, stream>>>(fc_w, fc_wT, NH, 7);
  init_bar_kernel<<<1, 256, 0, stream>>>(bar);

  {
    void* kargs[] = { (void*)&src, (void*)&lens, (void*)&proj, (void*)&Wt_hh0,
                      (void*)&Wt_xh1, (void*)&Wt_hh1, (void*)&b_xh1,
                      (void*)&h0_bufs, (void*)&h1_all, (void*)&bar };
    hipError_t e = hipLaunchCooperativeKernel((void*)rnn_persist, dim3(NBLK), dim3(256),
                                              kargs, 0, stream);
    if (e != hipSuccess) {
      // 128 blocks <= 256 CUs: co-resident on plain launch as well
      rnn_persist<<<NBLK, 256, 0, stream>>>(src, lens, proj, Wt_hh0, Wt_xh1,
                                            Wt_hh1, b_xh1, h0_bufs, h1_all, bar);
    }
  }

  out_gemm<<<NT, 256, 0, stream>>>(h1_all, fc_wT, fc_b, out);
}

// Round 3
// 2649.283 us; speedup vs baseline: 2.3693x; 2.3430x over previous
//
#include <hip/hip_runtime.h>
#include <hip/hip_bf16.h>

// Problem dims
constexpr int NB = 128;   // batch
constexpr int NT = 512;   // seq len
constexpr int NE = 256;   // embed dim
constexpr int NH = 512;   // hidden
constexpr int NV = 64;    // vocab
constexpr int NP = 128;   // output proj dim

// 8 independent row groups of 16 batch rows; per group 8 L0 + 8 L1 blocks,
// each owning a 64-col slice. Weights live in VGPRs (loop-invariant).
constexpr int GROUPS = 8;
constexpr int MR     = 16;    // batch rows per group
constexpr int NCS    = 64;    // hidden cols per block slice
constexpr int SLICES = 8;     // NH / NCS
constexpr int NBLK   = GROUPS * 2 * SLICES;   // 128 blocks
constexpr int RING   = 4;     // h0 ring depth

typedef unsigned short u16;
typedef __attribute__((ext_vector_type(8))) short bf16x8v;   // 8 bf16 (4 VGPRs)
typedef __attribute__((ext_vector_type(4))) float f32x4v;    // MFMA accumulator

__device__ __forceinline__ u16 f2bf(float x) {
  unsigned u = __builtin_bit_cast(unsigned, x);
  return (u16)((u + 0x7fffu + ((u >> 16) & 1u)) >> 16);  // RNE
}

// ---------------------------------------------------------------------------
__global__ __launch_bounds__(256) void proj_kernel(
    const float* __restrict__ emb, const float* __restrict__ W_xh0,
    const float* __restrict__ b_xh0, float* __restrict__ proj) {
  int v = blockIdx.x >> 1;
  int j = ((blockIdx.x & 1) << 8) + threadIdx.x;
  float acc = b_xh0[j];
  const float* er = emb + v * NE;
  for (int e = 0; e < NE; ++e) acc += er[e] * W_xh0[e * NH + j];
  proj[v * NH + j] = acc;
}

__global__ __launch_bounds__(256) void transpose_bf16_kernel(
    const float* __restrict__ src, u16* __restrict__ dst, int R, int logC) {
  int idx = blockIdx.x * 256 + threadIdx.x;
  int C = 1 << logC;
  if (idx >= R * C) return;
  int r = idx >> logC;
  int c = idx & (C - 1);
  dst[c * R + r] = f2bf(src[idx]);
}

__global__ void zero_flags_kernel(int* flags) {
  flags[blockIdx.x * 256 + threadIdx.x] = 0;   // 2048 ints
}

// ---------------------------------------------------------------------------
// Stage a 16x512 bf16 panel (row stride NH) into fragment-major swizzled LDS:
// frag kt (K-chunk of 32) holds 64 lanes x 16B; slot index = lane ^ kt.
// Global side coalesced (consecutive tid -> consecutive 16B); LDS writes and
// reads both bijective per wave -> conflict-free.
__device__ __forceinline__ void stage_A(const u16* __restrict__ gsrc,
                                        u16* __restrict__ buf, int tid) {
#pragma unroll
  for (int it = 0; it < 4; ++it) {
    int idx = it * 256 + tid;        // 0..1023
    int row = idx >> 6;              // 0..15
    int k8  = idx & 63;              // 8-elem group along K
    int kt  = k8 >> 2;               // 0..15
    int koct = k8 & 3;               // 0..3
    uint4 v = *(const uint4*)(gsrc + row * NH + k8 * 8);
    int slot = ((koct << 4) | row) ^ kt;
    *(uint4*)(buf + (kt << 9) + (slot << 3)) = v;
  }
}

__device__ __forceinline__ bf16x8v frag_A(const u16* __restrict__ buf,
                                          int kt, int lane) {
  return *(const bf16x8v*)(buf + (kt << 9) + (((lane ^ kt) & 63) << 3));
}

// ---------------------------------------------------------------------------
__global__ __launch_bounds__(256, 1) void rnn_persist(
    const int* __restrict__ src, const int* __restrict__ lens,
    const float* __restrict__ proj,
    const u16* __restrict__ Wt_hh0,   // [NH][NH] = W^T, bf16
    const u16* __restrict__ Wt_xh1,
    const u16* __restrict__ Wt_hh1,
    const float* __restrict__ b_xh1,
    u16* __restrict__ h0_ring,        // [RING][NB][NH]
    u16* __restrict__ h1_all,         // [NT][NB][NH]
    int* flags)                       // [2][GROUPS][SLICES][16] ints
{
  __shared__ struct {
    union {
      struct { float pj[NV][72]; int srcv[MR][NT]; u16 a0[16 * 512]; } l0;
      struct { u16 a0[16 * 512]; u16 a1[16 * 512]; } l1;
    } u;
    u16 rep[16][72];
  } sm;

  const int bid = blockIdx.x;
  const int g = bid & (GROUPS - 1);
  const int uu = bid >> 3;                 // 0..15 within group
  const bool is_l1 = (uu >= SLICES);
  const int slice = is_l1 ? (uu - SLICES) : uu;
  const int c0 = slice * NCS;
  const int r0 = g * MR;

  const int tid = threadIdx.x;
  const int lane = tid & 63, wave = tid >> 6;
  const int lq = lane >> 4, lr = lane & 15;
  const int n0 = wave * 16;                // col sub-tile within slice
  const size_t HS = (size_t)NB * NH;

  auto flag_at = [&](int layer, int sl) {
    return flags + (((layer << 3) | g) * SLICES + sl) * 16;
  };
  int* myflag = flag_at(is_l1 ? 1 : 0, slice);

  int ln[4];
#pragma unroll
  for (int i = 0; i < 4; ++i) ln[i] = lens[r0 + lq * 4 + i];
  u16 oreg[4] = {0, 0, 0, 0};

  if (!is_l1) {
    // =============================== layer 0 ===============================
    // one-time: weights -> VGPRs, pj slice + src rows -> LDS
    bf16x8v w0[16];
    {
      const u16* wp = Wt_hh0 + (size_t)(c0 + n0 + lr) * NH + lq * 8;
#pragma unroll
      for (int kt = 0; kt < 16; ++kt) w0[kt] = *(const bf16x8v*)(wp + kt * 32);
    }
#pragma unroll
    for (int it = 0; it < 4; ++it) {       // pj: 64 x 64 f32
      int c = it * 256 + tid;
      int v = c >> 4, j4 = (c & 15) * 4;
      *(float4*)&sm.u.l0.pj[v][j4] = *(const float4*)&proj[v * NH + c0 + j4];
    }
#pragma unroll
    for (int it = 0; it < 8; ++it)         // src rows: 16 x 512 int
      ((int4*)sm.u.l0.srcv)[it * 256 + tid] =
          ((const int4*)(src + (size_t)r0 * NT))[it * 256 + tid];
    __syncthreads();

    for (int s = 0; s < NT; ++s) {
      f32x4v acc = {0.f, 0.f, 0.f, 0.f};
      if (s > 0) {
        // wait: h0(s-1) from L0 sibs (flag >= s); ring WAR: L1 sibs >= s-2
        if (tid < 16) {
          int need = (tid < 8) ? s : ((s >= 4) ? s - 2 : 0);
          const int* fp = flag_at(tid < 8 ? 0 : 1, tid & 7);
          if (need > 0)
            while (__hip_atomic_load(fp, __ATOMIC_RELAXED,
                                     __HIP_MEMORY_SCOPE_AGENT) < need) {}
        }
        __builtin_amdgcn_fence(__ATOMIC_ACQUIRE, "agent");
        __syncthreads();
        stage_A(h0_ring + (size_t)((s - 1) & (RING - 1)) * HS + (size_t)r0 * NH,
                sm.u.l0.a0, tid);
        __syncthreads();
#pragma unroll
        for (int kt = 0; kt < 16; ++kt)
          acc = __builtin_amdgcn_mfma_f32_16x16x32_bf16(
              frag_A(sm.u.l0.a0, kt, lane), w0[kt], acc, 0, 0, 0);
      }
#pragma unroll
      for (int i = 0; i < 4; ++i) {
        int row = lq * 4 + i;
        int v = sm.u.l0.srcv[row][s];
        float pre = acc[i] + sm.u.l0.pj[v][n0 + lr];
        u16 o = (s < ln[i]) ? f2bf(tanhf(pre)) : oreg[i];
        oreg[i] = o;
        sm.rep[row][n0 + lr] = o;
      }
      __syncthreads();
      u16* hdst = h0_ring + (size_t)(s & (RING - 1)) * HS;
#pragma unroll
      for (int k = 0; k < 2; ++k) {
        int d = tid * 2 + k;               // 512 dwords = 16 rows x 32 col-pairs
        int row = d >> 5, cp = d & 31;
        unsigned val = *(const unsigned*)&sm.rep[row][cp * 2];
        __hip_atomic_store((unsigned*)(hdst + (size_t)(r0 + row) * NH + c0) + cp,
                           val, __ATOMIC_RELAXED, __HIP_MEMORY_SCOPE_AGENT);
      }
      asm volatile("s_waitcnt vmcnt(0)" ::: "memory");
      __syncthreads();
      if (tid == 0)
        __hip_atomic_store(myflag, s + 1, __ATOMIC_RELAXED,
                           __HIP_MEMORY_SCOPE_AGENT);
    }
  } else {
    // =============================== layer 1 ===============================
    bf16x8v wx[16], wh[16];
    {
      const u16* wpx = Wt_xh1 + (size_t)(c0 + n0 + lr) * NH + lq * 8;
      const u16* wph = Wt_hh1 + (size_t)(c0 + n0 + lr) * NH + lq * 8;
#pragma unroll
      for (int kt = 0; kt < 16; ++kt) {
        wx[kt] = *(const bf16x8v*)(wpx + kt * 32);
        wh[kt] = *(const bf16x8v*)(wph + kt * 32);
      }
    }
    const float bcol = b_xh1[c0 + n0 + lr];
    __syncthreads();

    for (int s = 1; s <= NT; ++s) {
      const int t = s - 1;
      // wait: h0(s-1) (L0 flags >= s); h1(s-2) (L1 sib flags >= s, s>=2)
      if (tid < 16) {
        int need = (tid < 8) ? s : ((s >= 2) ? s : 0);
        const int* fp = flag_at(tid < 8 ? 0 : 1, tid & 7);
        if (need > 0)
          while (__hip_atomic_load(fp, __ATOMIC_RELAXED,
                                   __HIP_MEMORY_SCOPE_AGENT) < need) {}
      }
      __builtin_amdgcn_fence(__ATOMIC_ACQUIRE, "agent");
      __syncthreads();
      stage_A(h0_ring + (size_t)((s - 1) & (RING - 1)) * HS + (size_t)r0 * NH,
              sm.u.l1.a0, tid);
      if (s >= 2)
        stage_A(h1_all + (size_t)(s - 2) * HS + (size_t)r0 * NH, sm.u.l1.a1, tid);
      __syncthreads();

      f32x4v acc = {0.f, 0.f, 0.f, 0.f};
#pragma unroll
      for (int kt = 0; kt < 16; ++kt)
        acc = __builtin_amdgcn_mfma_f32_16x16x32_bf16(
            frag_A(sm.u.l1.a0, kt, lane), wx[kt], acc, 0, 0, 0);
      if (s >= 2) {
#pragma unroll
        for (int kt = 0; kt < 16; ++kt)
          acc = __builtin_amdgcn_mfma_f32_16x16x32_bf16(
              frag_A(sm.u.l1.a1, kt, lane), wh[kt], acc, 0, 0, 0);
      }
#pragma unroll
      for (int i = 0; i < 4; ++i) {
        int row = lq * 4 + i;
        float pre = acc[i] + bcol;
        u16 o = (t < ln[i]) ? f2bf(tanhf(pre)) : oreg[i];
        oreg[i] = o;
        sm.rep[row][n0 + lr] = o;
      }
      __syncthreads();
      u16* hdst = h1_all + (size_t)t * HS;
#pragma unroll
      for (int k = 0; k < 2; ++k) {
        int d = tid * 2 + k;
        int row = d >> 5, cp = d & 31;
        unsigned val = *(const unsigned*)&sm.rep[row][cp * 2];
        __hip_atomic_store((unsigned*)(hdst + (size_t)(r0 + row) * NH + c0) + cp,
                           val, __ATOMIC_RELAXED, __HIP_MEMORY_SCOPE_AGENT);
      }
      asm volatile("s_waitcnt vmcnt(0)" ::: "memory");
      __syncthreads();
      if (tid == 0)
        __hip_atomic_store(myflag, s + 1, __ATOMIC_RELAXED,
                           __HIP_MEMORY_SCOPE_AGENT);
    }
  }
}

// ---------------------------------------------------------------------------
__global__ __launch_bounds__(256) void out_gemm(
    const u16* __restrict__ h1_all, const u16* __restrict__ fc_wT,
    const float* __restrict__ fc_b, float* __restrict__ out)
{
  const int t = blockIdx.x;
  const int tid = threadIdx.x, lane = tid & 63, wave = tid >> 6;
  const int lq = lane >> 4, lr = lane & 15;
  const int m0 = wave * 32;
  f32x4v acc[2][8];
#pragma unroll
  for (int a = 0; a < 2; ++a)
#pragma unroll
    for (int b = 0; b < 8; ++b) acc[a][b] = (f32x4v){0.f, 0.f, 0.f, 0.f};

  const u16* a0p = h1_all + ((size_t)t * NB + m0 + lr) * NH;
  const u16* a1p = a0p + 16 * NH;
#pragma unroll 2
  for (int kt = 0; kt < 16; ++kt) {
    int kb = kt * 32 + lq * 8;
    bf16x8v a0 = *(const bf16x8v*)(a0p + kb);
    bf16x8v a1 = *(const bf16x8v*)(a1p + kb);
#pragma unroll
    for (int ni = 0; ni < 8; ++ni) {
      bf16x8v bb = *(const bf16x8v*)(fc_wT + (size_t)(ni * 16 + lr) * NH + kb);
      acc[0][ni] = __builtin_amdgcn_mfma_f32_16x16x32_bf16(a0, bb, acc[0][ni], 0, 0, 0);
      acc[1][ni] = __builtin_amdgcn_mfma_f32_16x16x32_bf16(a1, bb, acc[1][ni], 0, 0, 0);
    }
  }
#pragma unroll
  for (int mi = 0; mi < 2; ++mi)
#pragma unroll
    for (int ni = 0; ni < 8; ++ni)
#pragma unroll
      for (int i = 0; i < 4; ++i) {
        int b_ = m0 + mi * 16 + lq * 4 + i;
        int p = ni * 16 + lr;
        out[((size_t)b_ * NT + t) * NP + p] = acc[mi][ni][i] + fc_b[p];
      }
}

// ---------------------------------------------------------------------------
extern "C" void kernel_launch(void* const* d_in, const int* in_sizes, int n_in,
                              void* d_out, int out_size, void* d_ws, size_t ws_size,
                              hipStream_t stream) {
  const int*   src   = (const int*)  d_in[0];
  const int*   lens  = (const int*)  d_in[1];
  const float* emb   = (const float*)d_in[2];
  const float* W_xh0 = (const float*)d_in[3];
  const float* b_xh0 = (const float*)d_in[4];
  const float* W_hh0 = (const float*)d_in[5];
  const float* W_xh1 = (const float*)d_in[6];
  const float* b_xh1 = (const float*)d_in[7];
  const float* W_hh1 = (const float*)d_in[8];
  const float* fc_w  = (const float*)d_in[9];
  const float* fc_b  = (const float*)d_in[10];
  float* out = (float*)d_out;

  char* ws = (char*)d_ws;
  auto alloc = [&](size_t bytes) { char* p = ws; ws += (bytes + 255) & ~size_t(255); return p; };
  float* proj   = (float*)alloc(NV * NH * 4);
  u16* Wt_hh0   = (u16*)  alloc(NH * NH * 2);
  u16* Wt_xh1   = (u16*)  alloc(NH * NH * 2);
  u16* Wt_hh1   = (u16*)  alloc(NH * NH * 2);
  u16* fc_wT    = (u16*)  alloc(NP * NH * 2);
  u16* h0_ring  = (u16*)  alloc((size_t)RING * NB * NH * 2);
  u16* h1_all   = (u16*)  alloc((size_t)NT * NB * NH * 2);
  int* flags    = (int*)  alloc(2 * GROUPS * SLICES * 16 * 4);

  proj_kernel<<<NV * 2, 256, 0, stream>>>(emb, W_xh0, b_xh0, proj);
  transpose_bf16_kernel<<<(NH * NH + 255) / 256, 256, 0, stream>>>(W_hh0, Wt_hh0, NH, 9);
  transpose_bf16_kernel<<<(NH * NH + 255) / 256, 256, 0, stream>>>(W_xh1, Wt_xh1, NH, 9);
  transpose_bf16_kernel<<<(NH * NH + 255) / 256, 256, 0, stream>>>(W_hh1, Wt_hh1, NH, 9);
  transpose_bf16_kernel<<<(NH * NP + 255) / 256, 256, 0, stream>>>(fc_w, fc_wT, NH, 7);
  zero_flags_kernel<<<8, 256, 0, stream>>>(flags);

  {
    void* kargs[] = { (void*)&src, (void*)&lens, (void*)&proj, (void*)&Wt_hh0,
                      (void*)&Wt_xh1, (void*)&Wt_hh1, (void*)&b_xh1,
                      (void*)&h0_ring, (void*)&h1_all, (void*)&flags };
    hipError_t e = hipLaunchCooperativeKernel((void*)rnn_persist, dim3(NBLK), dim3(256),
                                              kargs, 0, stream);
    if (e != hipSuccess) {
      rnn_persist<<<NBLK, 256, 0, stream>>>(src, lens, proj, Wt_hh0, Wt_xh1,
                                            Wt_hh1, b_xh1, h0_ring, h1_all, flags);
    }
  }

  out_gemm<<<NT, 256, 0, stream>>>(h1_all, fc_wT, fc_b, out);
}

// Round 4
// 2070.290 us; speedup vs baseline: 3.0319x; 1.2797x over previous
//
#include <hip/hip_runtime.h>
#include <hip/hip_bf16.h>

// Problem dims
constexpr int NB = 128;   // batch
constexpr int NT = 512;   // seq len
constexpr int NE = 256;   // embed dim
constexpr int NH = 512;   // hidden
constexpr int NV = 64;    // vocab
constexpr int NP = 128;   // output proj dim

// 8 independent row groups of 16 batch rows; per group 8 merged blocks
// (512 threads: waves 0-3 layer-0, waves 4-7 layer-1), each owning a 64-col
// slice of BOTH layers. Weights live in VGPRs (loop-invariant).
constexpr int GROUPS = 8;
constexpr int MR     = 16;    // batch rows per group
constexpr int NCS    = 64;    // hidden cols per block slice
constexpr int SLICES = 8;     // NH / NCS
constexpr int NBLK   = GROUPS * SLICES;   // 64 blocks
constexpr int RING   = 16;    // h0 ring depth

typedef unsigned short u16;
typedef __attribute__((ext_vector_type(8))) short bf16x8v;   // 8 bf16 (4 VGPRs)
typedef __attribute__((ext_vector_type(4))) float f32x4v;    // MFMA accumulator

__device__ __forceinline__ u16 f2bf(float x) {
  unsigned u = __builtin_bit_cast(unsigned, x);
  return (u16)((u + 0x7fffu + ((u >> 16) & 1u)) >> 16);  // RNE
}

// ---------------------------------------------------------------------------
__global__ __launch_bounds__(256) void proj_kernel(
    const float* __restrict__ emb, const float* __restrict__ W_xh0,
    const float* __restrict__ b_xh0, float* __restrict__ proj) {
  int v = blockIdx.x >> 1;
  int j = ((blockIdx.x & 1) << 8) + threadIdx.x;
  float acc = b_xh0[j];
  const float* er = emb + v * NE;
  for (int e = 0; e < NE; ++e) acc += er[e] * W_xh0[e * NH + j];
  proj[v * NH + j] = acc;
}

__global__ __launch_bounds__(256) void transpose_bf16_kernel(
    const float* __restrict__ src, u16* __restrict__ dst, int R, int logC) {
  int idx = blockIdx.x * 256 + threadIdx.x;
  int C = 1 << logC;
  if (idx >= R * C) return;
  int r = idx >> logC;
  int c = idx & (C - 1);
  dst[c * R + r] = f2bf(src[idx]);
}

__global__ void zero_flags_kernel(int* flags) {
  flags[blockIdx.x * 256 + threadIdx.x] = 0;   // 1024 ints
}

// ---------------------------------------------------------------------------
// Stage a 16x512 bf16 panel (row stride NH) into fragment-major swizzled LDS.
// frag kt (K-chunk of 32) holds 64 lanes x 16B; slot = ((koct<<4)|row) ^ kt.
// Coalesced global reads; bijective LDS writes/reads per wave (conflict-free).
__device__ __forceinline__ void stage_panel(const u16* __restrict__ gsrc,
                                            u16* __restrict__ buf, int tid) {
#pragma unroll
  for (int it = 0; it < 2; ++it) {
    int idx = it * 512 + tid;        // 0..1023
    int row = idx >> 6;              // 0..15
    int k8  = idx & 63;              // 8-elem group along K
    int kt  = k8 >> 2;               // 0..15
    int koct = k8 & 3;               // 0..3
    uint4 v = *(const uint4*)(gsrc + row * NH + k8 * 8);
    int slot = ((koct << 4) | row) ^ kt;
    *(uint4*)(buf + (kt << 9) + (slot << 3)) = v;
  }
}

__device__ __forceinline__ bf16x8v frag_A(const u16* __restrict__ buf,
                                          int kt, int lane) {
  return *(const bf16x8v*)(buf + (kt << 9) + (((lane ^ kt) & 63) << 3));
}

// ---------------------------------------------------------------------------
__global__ __launch_bounds__(512, 1) void rnn_persist(
    const int* __restrict__ src, const int* __restrict__ lens,
    const float* __restrict__ proj,
    const u16* __restrict__ Wt_hh0,   // [NH][NH] = W^T, bf16
    const u16* __restrict__ Wt_xh1,
    const u16* __restrict__ Wt_hh1,
    const float* __restrict__ b_xh1,
    u16* __restrict__ h0_ring,        // [RING][NB][NH]
    u16* __restrict__ h1_all,         // [NT][NB][NH]
    int* flags)                       // [GROUPS][SLICES][16] ints
{
  __shared__ struct {
    u16 a0[16 * 512];    // h0(s-1) panel
    u16 a1[16 * 512];    // h1(s-2) panel
    float pj[NV][72];
    int srcv[MR][NT];
    u16 rep0[16][72];
    u16 rep1[16][72];
  } sm;

  const int bid = blockIdx.x;
  const int g = bid & (GROUPS - 1);        // group -> same XCD residue class
  const int slice = bid >> 3;
  const int c0 = slice * NCS;
  const int r0 = g * MR;

  const int tid = threadIdx.x;
  const int lane = tid & 63, wave = tid >> 6;
  const int lq = lane >> 4, lr = lane & 15;
  const bool l1w = (wave >= 4);            // waves 4-7: layer 1
  const int n0 = (wave & 3) * 16;          // col sub-tile within slice
  const size_t HS = (size_t)NB * NH;

  int* myflag = flags + (g * SLICES + slice) * 16;

  // ---- one-time: weights -> VGPRs (role-dependent), pj + src -> LDS ----
  bf16x8v w0[16], wx[16], wh[16];
  if (!l1w) {
    const u16* wp = Wt_hh0 + (size_t)(c0 + n0 + lr) * NH + lq * 8;
#pragma unroll
    for (int kt = 0; kt < 16; ++kt) w0[kt] = *(const bf16x8v*)(wp + kt * 32);
  } else {
    const u16* wpx = Wt_xh1 + (size_t)(c0 + n0 + lr) * NH + lq * 8;
    const u16* wph = Wt_hh1 + (size_t)(c0 + n0 + lr) * NH + lq * 8;
#pragma unroll
    for (int kt = 0; kt < 16; ++kt) {
      wx[kt] = *(const bf16x8v*)(wpx + kt * 32);
      wh[kt] = *(const bf16x8v*)(wph + kt * 32);
    }
  }
  const float bcol = l1w ? b_xh1[c0 + n0 + lr] : 0.f;

#pragma unroll
  for (int it = 0; it < 2; ++it) {         // pj: 64 x 64 f32
    int c = it * 512 + tid;
    int v = c >> 4, j4 = (c & 15) * 4;
    *(float4*)&sm.pj[v][j4] = *(const float4*)&proj[v * NH + c0 + j4];
  }
#pragma unroll
  for (int it = 0; it < 4; ++it)           // src rows: 16 x 512 int
    ((int4*)sm.srcv)[it * 512 + tid] =
        ((const int4*)(src + (size_t)r0 * NT))[it * 512 + tid];

  int ln[4];
#pragma unroll
  for (int i = 0; i < 4; ++i) ln[i] = lens[r0 + lq * 4 + i];
  u16 oreg[4] = {0, 0, 0, 0};
  __syncthreads();

  for (int s = 0; s <= NT; ++s) {
    if (s > 0) {
      // wait: all 8 group sibs published stage s-1 (h0(s-1), h1(s-2))
      if (tid < 8) {
        const int* fp = flags + (g * SLICES + tid) * 16;
        while (__hip_atomic_load(fp, __ATOMIC_RELAXED,
                                 __HIP_MEMORY_SCOPE_AGENT) < s) {}
      }
      if (tid < 64) __builtin_amdgcn_fence(__ATOMIC_ACQUIRE, "agent");
      __syncthreads();
      stage_panel(h0_ring + (size_t)((s - 1) & (RING - 1)) * HS + (size_t)r0 * NH,
                  sm.a0, tid);
      if (s >= 2)
        stage_panel(h1_all + (size_t)(s - 2) * HS + (size_t)r0 * NH, sm.a1, tid);
      __syncthreads();
    }

    if (!l1w) {
      // ---------------- layer 0: h0(s) ----------------
      if (s < NT) {
        f32x4v acc = {0.f, 0.f, 0.f, 0.f};
        if (s > 0) {
#pragma unroll
          for (int kt = 0; kt < 16; ++kt)
            acc = __builtin_amdgcn_mfma_f32_16x16x32_bf16(
                frag_A(sm.a0, kt, lane), w0[kt], acc, 0, 0, 0);
        }
#pragma unroll
        for (int i = 0; i < 4; ++i) {
          int row = lq * 4 + i;
          int v = sm.srcv[row][s];
          float pre = acc[i] + sm.pj[v][n0 + lr];
          u16 o = (s < ln[i]) ? f2bf(tanhf(pre)) : oreg[i];
          oreg[i] = o;
          sm.rep0[row][n0 + lr] = o;
        }
      }
    } else {
      // ---------------- layer 1: h1(s-1) ----------------
      if (s >= 1) {
        const int t = s - 1;
        f32x4v acc = {0.f, 0.f, 0.f, 0.f};
#pragma unroll
        for (int kt = 0; kt < 16; ++kt)
          acc = __builtin_amdgcn_mfma_f32_16x16x32_bf16(
              frag_A(sm.a0, kt, lane), wx[kt], acc, 0, 0, 0);
        if (s >= 2) {
#pragma unroll
          for (int kt = 0; kt < 16; ++kt)
            acc = __builtin_amdgcn_mfma_f32_16x16x32_bf16(
                frag_A(sm.a1, kt, lane), wh[kt], acc, 0, 0, 0);
        }
#pragma unroll
        for (int i = 0; i < 4; ++i) {
          int row = lq * 4 + i;
          float pre = acc[i] + bcol;
          u16 o = (t < ln[i]) ? f2bf(tanhf(pre)) : oreg[i];
          oreg[i] = o;
          sm.rep1[row][n0 + lr] = o;
        }
      }
    }
    __syncthreads();

    // ---- publish: h0 slice -> ring, h1 slice -> h1_all; 2 dwords/thread ----
#pragma unroll
    for (int k = 0; k < 2; ++k) {
      int d = tid * 2 + k;                 // 0..1023
      int panel = d >> 9, e = d & 511;
      int row = e >> 5, cp = e & 31;
      if (panel == 0) {
        if (s < NT) {
          unsigned val = *(const unsigned*)&sm.rep0[row][cp * 2];
          __hip_atomic_store(
              (unsigned*)(h0_ring + (size_t)(s & (RING - 1)) * HS +
                          (size_t)(r0 + row) * NH + c0) + cp,
              val, __ATOMIC_RELAXED, __HIP_MEMORY_SCOPE_AGENT);
        }
      } else if (s >= 1) {
        unsigned val = *(const unsigned*)&sm.rep1[row][cp * 2];
        __hip_atomic_store(
            (unsigned*)(h1_all + (size_t)(s - 1) * HS +
                        (size_t)(r0 + row) * NH + c0) + cp,
            val, __ATOMIC_RELAXED, __HIP_MEMORY_SCOPE_AGENT);
      }
    }
    asm volatile("s_waitcnt vmcnt(0)" ::: "memory");
    __syncthreads();
    if (tid == 0)
      __hip_atomic_store(myflag, s + 1, __ATOMIC_RELAXED,
                         __HIP_MEMORY_SCOPE_AGENT);
  }
}

// ---------------------------------------------------------------------------
__global__ __launch_bounds__(256) void out_gemm(
    const u16* __restrict__ h1_all, const u16* __restrict__ fc_wT,
    const float* __restrict__ fc_b, float* __restrict__ out)
{
  const int t = blockIdx.x;
  const int tid = threadIdx.x, lane = tid & 63, wave = tid >> 6;
  const int lq = lane >> 4, lr = lane & 15;
  const int m0 = wave * 32;
  f32x4v acc[2][8];
#pragma unroll
  for (int a = 0; a < 2; ++a)
#pragma unroll
    for (int b = 0; b < 8; ++b) acc[a][b] = (f32x4v){0.f, 0.f, 0.f, 0.f};

  const u16* a0p = h1_all + ((size_t)t * NB + m0 + lr) * NH;
  const u16* a1p = a0p + 16 * NH;
#pragma unroll 2
  for (int kt = 0; kt < 16; ++kt) {
    int kb = kt * 32 + lq * 8;
    bf16x8v a0 = *(const bf16x8v*)(a0p + kb);
    bf16x8v a1 = *(const bf16x8v*)(a1p + kb);
#pragma unroll
    for (int ni = 0; ni < 8; ++ni) {
      bf16x8v bb = *(const bf16x8v*)(fc_wT + (size_t)(ni * 16 + lr) * NH + kb);
      acc[0][ni] = __builtin_amdgcn_mfma_f32_16x16x32_bf16(a0, bb, acc[0][ni], 0, 0, 0);
      acc[1][ni] = __builtin_amdgcn_mfma_f32_16x16x32_bf16(a1, bb, acc[1][ni], 0, 0, 0);
    }
  }
#pragma unroll
  for (int mi = 0; mi < 2; ++mi)
#pragma unroll
    for (int ni = 0; ni < 8; ++ni)
#pragma unroll
      for (int i = 0; i < 4; ++i) {
        int b_ = m0 + mi * 16 + lq * 4 + i;
        int p = ni * 16 + lr;
        out[((size_t)b_ * NT + t) * NP + p] = acc[mi][ni][i] + fc_b[p];
      }
}

// ---------------------------------------------------------------------------
extern "C" void kernel_launch(void* const* d_in, const int* in_sizes, int n_in,
                              void* d_out, int out_size, void* d_ws, size_t ws_size,
                              hipStream_t stream) {
  const int*   src   = (const int*)  d_in[0];
  const int*   lens  = (const int*)  d_in[1];
  const float* emb   = (const float*)d_in[2];
  const float* W_xh0 = (const float*)d_in[3];
  const float* b_xh0 = (const float*)d_in[4];
  const float* W_hh0 = (const float*)d_in[5];
  const float* W_xh1 = (const float*)d_in[6];
  const float* b_xh1 = (const float*)d_in[7];
  const float* W_hh1 = (const float*)d_in[8];
  const float* fc_w  = (const float*)d_in[9];
  const float* fc_b  = (const float*)d_in[10];
  float* out = (float*)d_out;

  char* ws = (char*)d_ws;
  auto alloc = [&](size_t bytes) { char* p = ws; ws += (bytes + 255) & ~size_t(255); return p; };
  float* proj   = (float*)alloc(NV * NH * 4);
  u16* Wt_hh0   = (u16*)  alloc(NH * NH * 2);
  u16* Wt_xh1   = (u16*)  alloc(NH * NH * 2);
  u16* Wt_hh1   = (u16*)  alloc(NH * NH * 2);
  u16* fc_wT    = (u16*)  alloc(NP * NH * 2);
  u16* h0_ring  = (u16*)  alloc((size_t)RING * NB * NH * 2);
  u16* h1_all   = (u16*)  alloc((size_t)NT * NB * NH * 2);
  int* flags    = (int*)  alloc(GROUPS * SLICES * 16 * 4);

  proj_kernel<<<NV * 2, 256, 0, stream>>>(emb, W_xh0, b_xh0, proj);
  transpose_bf16_kernel<<<(NH * NH + 255) / 256, 256, 0, stream>>>(W_hh0, Wt_hh0, NH, 9);
  transpose_bf16_kernel<<<(NH * NH + 255) / 256, 256, 0, stream>>>(W_xh1, Wt_xh1, NH, 9);
  transpose_bf16_kernel<<<(NH * NH + 255) / 256, 256, 0, stream>>>(W_hh1, Wt_hh1, NH, 9);
  transpose_bf16_kernel<<<(NH * NP + 255) / 256, 256, 0, stream>>>(fc_w, fc_wT, NH, 7);
  zero_flags_kernel<<<4, 256, 0, stream>>>(flags);

  {
    void* kargs[] = { (void*)&src, (void*)&lens, (void*)&proj, (void*)&Wt_hh0,
                      (void*)&Wt_xh1, (void*)&Wt_hh1, (void*)&b_xh1,
                      (void*)&h0_ring, (void*)&h1_all, (void*)&flags };
    hipError_t e = hipLaunchCooperativeKernel((void*)rnn_persist, dim3(NBLK), dim3(512),
                                              kargs, 0, stream);
    if (e != hipSuccess) {
      rnn_persist<<<NBLK, 512, 0, stream>>>(src, lens, proj, Wt_hh0, Wt_xh1,
                                            Wt_hh1, b_xh1, h0_ring, h1_all, flags);
    }
  }

  out_gemm<<<NT, 256, 0, stream>>>(h1_all, fc_wT, fc_b, out);
}